// Round 2
// baseline (214.151 us; speedup 1.0000x reference)
//
#include <hip/hip_runtime.h>

#define N_NODES 4096
#define B_PTS   4096
#define SUPPORT_FACTOR 2.5f
#define EPSILON 1e-5f

typedef float fx4 __attribute__((ext_vector_type(4)));

// ---------------------------------------------------------------------------
// Kernel 1: per-node nearest-neighbor distance (~4 us). One block per node.
// ---------------------------------------------------------------------------
__global__ __launch_bounds__(256) void nearest_kernel(
        const float* __restrict__ nodes, float* __restrict__ mind) {
    const int i = blockIdx.x;
    const float xi = nodes[2 * i];
    const float yi = nodes[2 * i + 1];

    const fx4* nodes4 = (const fx4*)nodes;  // 2 nodes per fx4
    float mind2 = 3.4e38f;
    for (int k = threadIdx.x; k < N_NODES / 2; k += 256) {
        fx4 v = nodes4[k];
        float dx0 = xi - v.x, dy0 = yi - v.y;
        float dx1 = xi - v.z, dy1 = yi - v.w;
        float d20 = dx0 * dx0 + dy0 * dy0;
        float d21 = dx1 * dx1 + dy1 * dy1;
        if (2 * k != i)     mind2 = fminf(mind2, d20);
        if (2 * k + 1 != i) mind2 = fminf(mind2, d21);
    }
    #pragma unroll
    for (int off = 32; off > 0; off >>= 1)
        mind2 = fminf(mind2, __shfl_down(mind2, off, 64));

    __shared__ float sw[4];
    const int wave = threadIdx.x >> 6;
    if ((threadIdx.x & 63) == 0) sw[wave] = mind2;
    __syncthreads();
    if (threadIdx.x == 0) {
        float m = fminf(fminf(sw[0], sw[1]), fminf(sw[2], sw[3]));
        mind[i] = sqrtf(m);
    }
}

// ---------------------------------------------------------------------------
// Cubic spline weight (zero outside q > 1)
// ---------------------------------------------------------------------------
__device__ __forceinline__ float cubic_w(float q) {
    if (q <= 0.5f) return 2.0f / 3.0f + q * q * (4.0f * q - 4.0f);
    if (q <= 1.0f) return 4.0f / 3.0f + q * (-4.0f + q * (4.0f - (4.0f / 3.0f) * q));
    return 0.0f;
}

// ---------------------------------------------------------------------------
// Kernel 2 (fused, single store pass): one block per query point b.
//  Phase 0: per-block redundant reduce of mind[] -> inv_dil, r^2 cutoff
//           (~300 cyc; cheaper than a dedicated 1-block launch + gap)
//  Phase 1: moment matrix over all nodes, 4-node-group early-out on
//           min(d^2) > r2m (skipped groups contribute exactly 0 to M)
//  Phase 2: tid 0 analytic adjugate inverse (negated deriv rows)
//  Phase 3: ONE dense coalesced store pass; per 4-node group either the
//           computed values or an exact-zero float4 (same bytes as any
//           dense write; no zero-then-scatter double traffic). Stores are
//           nontemporal: output is never re-read by us.
// ---------------------------------------------------------------------------
__global__ __launch_bounds__(256) void rkpm_kernel(
        const float* __restrict__ x, const float* __restrict__ nodes,
        const float* __restrict__ mind, float* __restrict__ out) {
    __shared__ float sred[4][6];
    __shared__ float sbc[10];

    const int b = blockIdx.x;
    const int tid = threadIdx.x;
    const int wave = tid >> 6;
    const int lane = tid & 63;

    // ---- phase 0: dilation from mind[] ----
    const fx4* m4 = (const fx4*)mind;
    float s = 0.f;
    #pragma unroll
    for (int k = 0; k < 4; ++k) {
        fx4 v = m4[k * 256 + tid];
        s += (v.x + v.y) + (v.z + v.w);
    }
    #pragma unroll
    for (int off = 32; off > 0; off >>= 1)
        s += __shfl_down(s, off, 64);
    if (lane == 0) sred[wave][0] = s;
    __syncthreads();
    if (tid == 0) {
        float dil = (sred[0][0] + sred[1][0] + sred[2][0] + sred[3][0]) *
                    (SUPPORT_FACTOR / (float)N_NODES);
        sbc[0] = 1.0f / dil;
        // margin 2e-4 relative >> sqrt/div rounding: never skips a w!=0 node
        sbc[1] = dil * dil * 1.0002f + 1e-9f;
    }
    __syncthreads();
    const float inv_dil = sbc[0];
    const float r2m     = sbc[1];

    const float2 xq = ((const float2*)x)[b];
    const float xb = xq.x, yb = xq.y;

    // ---- phase 1: moment matrix with early-out ----
    const fx4* nodes4 = (const fx4*)nodes;   // 2 nodes per fx4
    float m00 = 0.f, m01 = 0.f, m02 = 0.f, m11 = 0.f, m12 = 0.f, m22 = 0.f;
    #pragma unroll
    for (int kk = 0; kk < 4; ++kk) {
        fx4 va = nodes4[kk * 512 + 2 * tid];      // nodes j, j+1
        fx4 vb = nodes4[kk * 512 + 2 * tid + 1];  // nodes j+2, j+3
        float dx0 = xb - va.x, dy0 = yb - va.y;
        float dx1 = xb - va.z, dy1 = yb - va.w;
        float dx2 = xb - vb.x, dy2 = yb - vb.y;
        float dx3 = xb - vb.z, dy3 = yb - vb.w;
        float d0 = dx0 * dx0 + dy0 * dy0;
        float d1 = dx1 * dx1 + dy1 * dy1;
        float d2 = dx2 * dx2 + dy2 * dy2;
        float d3 = dx3 * dx3 + dy3 * dy3;
        float dmin = fminf(fminf(d0, d1), fminf(d2, d3));
        if (dmin <= r2m) {
            float w0 = cubic_w(sqrtf(d0 + 1e-10f) * inv_dil);
            float w1 = cubic_w(sqrtf(d1 + 1e-10f) * inv_dil);
            float w2 = cubic_w(sqrtf(d2 + 1e-10f) * inv_dil);
            float w3 = cubic_w(sqrtf(d3 + 1e-10f) * inv_dil);
            m00 += (w0 + w1) + (w2 + w3);
            m01 += (w0 * dx0 + w1 * dx1) + (w2 * dx2 + w3 * dx3);
            m02 += (w0 * dy0 + w1 * dy1) + (w2 * dy2 + w3 * dy3);
            m11 += (w0 * dx0 * dx0 + w1 * dx1 * dx1) + (w2 * dx2 * dx2 + w3 * dx3 * dx3);
            m12 += (w0 * dx0 * dy0 + w1 * dx1 * dy1) + (w2 * dx2 * dy2 + w3 * dx3 * dy3);
            m22 += (w0 * dy0 * dy0 + w1 * dy1 * dy1) + (w2 * dy2 * dy2 + w3 * dy3 * dy3);
        }
    }
    #pragma unroll
    for (int off = 32; off > 0; off >>= 1) {
        m00 += __shfl_down(m00, off, 64);
        m01 += __shfl_down(m01, off, 64);
        m02 += __shfl_down(m02, off, 64);
        m11 += __shfl_down(m11, off, 64);
        m12 += __shfl_down(m12, off, 64);
        m22 += __shfl_down(m22, off, 64);
    }
    if (lane == 0) {
        sred[wave][0] = m00; sred[wave][1] = m01; sred[wave][2] = m02;
        sred[wave][3] = m11; sred[wave][4] = m12; sred[wave][5] = m22;
    }
    __syncthreads();

    // ---- phase 2: analytic symmetric 3x3 inverse ----
    if (tid == 0) {
        float a  = sred[0][0] + sred[1][0] + sred[2][0] + sred[3][0] + EPSILON;
        float bb = sred[0][1] + sred[1][1] + sred[2][1] + sred[3][1];
        float c  = sred[0][2] + sred[1][2] + sred[2][2] + sred[3][2];
        float d  = sred[0][3] + sred[1][3] + sred[2][3] + sred[3][3] + EPSILON;
        float e  = sred[0][4] + sred[1][4] + sred[2][4] + sred[3][4];
        float f  = sred[0][5] + sred[1][5] + sred[2][5] + sred[3][5] + EPSILON;
        float c00 = d * f - e * e;
        float c01 = c * e - bb * f;
        float c02 = bb * e - c * d;
        float det = a * c00 + bb * c01 + c * c02;
        float idet = 1.0f / det;
        float i00 = c00 * idet;
        float i01 = c01 * idet;
        float i02 = c02 * idet;
        float i11 = (a * f - c * c) * idet;
        float i12 = (bb * c - a * e) * idet;
        float i22 = (a * d - bb * bb) * idet;
        sbc[1] = i00;  sbc[2] = i01;  sbc[3] = i02;   // phi row
        sbc[4] = -i01; sbc[5] = -i11; sbc[6] = -i12;  // phi_x row (negated)
        sbc[7] = -i02; sbc[8] = -i12; sbc[9] = -i22;  // phi_y row (negated)
    }
    __syncthreads();

    const float i00 = sbc[1], i01 = sbc[2], i02  = sbc[3];
    const float n01 = sbc[4], n11 = sbc[5], n12  = sbc[6];
    const float n02 = sbc[7], n12b = sbc[8], n22 = sbc[9];

    const size_t BN = (size_t)B_PTS * N_NODES;
    fx4* __restrict__ out_phi = (fx4*)(out + (size_t)b * N_NODES);
    fx4* __restrict__ out_px  = (fx4*)(out + BN + (size_t)b * N_NODES);
    fx4* __restrict__ out_py  = (fx4*)(out + 2 * BN + (size_t)b * N_NODES);

    // ---- phase 3: single dense pass, group early-out, nontemporal stores ----
    #pragma unroll
    for (int kk = 0; kk < 4; ++kk) {
        fx4 va = nodes4[kk * 512 + 2 * tid];
        fx4 vb = nodes4[kk * 512 + 2 * tid + 1];
        float dx0 = xb - va.x, dy0 = yb - va.y;
        float dx1 = xb - va.z, dy1 = yb - va.w;
        float dx2 = xb - vb.x, dy2 = yb - vb.y;
        float dx3 = xb - vb.z, dy3 = yb - vb.w;
        float d0 = dx0 * dx0 + dy0 * dy0;
        float d1 = dx1 * dx1 + dy1 * dy1;
        float d2 = dx2 * dx2 + dy2 * dy2;
        float d3 = dx3 * dx3 + dy3 * dy3;
        float dmin = fminf(fminf(d0, d1), fminf(d2, d3));

        fx4 ph = {0.f, 0.f, 0.f, 0.f};
        fx4 px = {0.f, 0.f, 0.f, 0.f};
        fx4 py = {0.f, 0.f, 0.f, 0.f};
        if (dmin <= r2m) {
            float w0 = cubic_w(sqrtf(d0 + 1e-10f) * inv_dil);
            float w1 = cubic_w(sqrtf(d1 + 1e-10f) * inv_dil);
            float w2 = cubic_w(sqrtf(d2 + 1e-10f) * inv_dil);
            float w3 = cubic_w(sqrtf(d3 + 1e-10f) * inv_dil);
            ph.x = w0 * (i00 + i01 * dx0 + i02 * dy0);
            ph.y = w1 * (i00 + i01 * dx1 + i02 * dy1);
            ph.z = w2 * (i00 + i01 * dx2 + i02 * dy2);
            ph.w = w3 * (i00 + i01 * dx3 + i02 * dy3);
            px.x = w0 * (n01 + n11 * dx0 + n12 * dy0);
            px.y = w1 * (n01 + n11 * dx1 + n12 * dy1);
            px.z = w2 * (n01 + n11 * dx2 + n12 * dy2);
            px.w = w3 * (n01 + n11 * dx3 + n12 * dy3);
            py.x = w0 * (n02 + n12b * dx0 + n22 * dy0);
            py.y = w1 * (n02 + n12b * dx1 + n22 * dy1);
            py.z = w2 * (n02 + n12b * dx2 + n22 * dy2);
            py.w = w3 * (n02 + n12b * dx3 + n22 * dy3);
        }
        const int idx = kk * 256 + tid;
        __builtin_nontemporal_store(ph, out_phi + idx);
        __builtin_nontemporal_store(px, out_px + idx);
        __builtin_nontemporal_store(py, out_py + idx);
    }
}

extern "C" void kernel_launch(void* const* d_in, const int* in_sizes, int n_in,
                              void* d_out, int out_size, void* d_ws, size_t ws_size,
                              hipStream_t stream) {
    const float* x     = (const float*)d_in[0];   // [4096, 2]
    const float* nodes = (const float*)d_in[1];   // [4096, 2]
    float* out  = (float*)d_out;                  // 3 * 4096 * 4096 floats
    float* mind = (float*)d_ws;                   // [4096] nearest distances

    nearest_kernel<<<N_NODES, 256, 0, stream>>>(nodes, mind);
    rkpm_kernel<<<B_PTS, 256, 0, stream>>>(x, nodes, mind, out);
}

// Round 3
// 210.864 us; speedup vs baseline: 1.0156x; 1.0156x over previous
//
#include <hip/hip_runtime.h>

#define N_NODES 4096
#define B_PTS   4096
#define SUPPORT_FACTOR 2.5f
#define EPSILON 1e-5f

typedef float fx4 __attribute__((ext_vector_type(4)));

// ---------------------------------------------------------------------------
// Kernel 1: per-node nearest-neighbor distance (~4 us). One block per node.
// ---------------------------------------------------------------------------
__global__ __launch_bounds__(256) void nearest_kernel(
        const float* __restrict__ nodes, float* __restrict__ mind) {
    const int i = blockIdx.x;
    const float xi = nodes[2 * i];
    const float yi = nodes[2 * i + 1];

    const fx4* nodes4 = (const fx4*)nodes;  // 2 nodes per fx4
    float mind2 = 3.4e38f;
    for (int k = threadIdx.x; k < N_NODES / 2; k += 256) {
        fx4 v = nodes4[k];
        float dx0 = xi - v.x, dy0 = yi - v.y;
        float dx1 = xi - v.z, dy1 = yi - v.w;
        float d20 = dx0 * dx0 + dy0 * dy0;
        float d21 = dx1 * dx1 + dy1 * dy1;
        if (2 * k != i)     mind2 = fminf(mind2, d20);
        if (2 * k + 1 != i) mind2 = fminf(mind2, d21);
    }
    #pragma unroll
    for (int off = 32; off > 0; off >>= 1)
        mind2 = fminf(mind2, __shfl_down(mind2, off, 64));

    __shared__ float sw[4];
    const int wave = threadIdx.x >> 6;
    if ((threadIdx.x & 63) == 0) sw[wave] = mind2;
    __syncthreads();
    if (threadIdx.x == 0) {
        float m = fminf(fminf(sw[0], sw[1]), fminf(sw[2], sw[3]));
        mind[i] = sqrtf(m);
    }
}

// ---------------------------------------------------------------------------
// Cubic spline weight (zero outside q > 1)
// ---------------------------------------------------------------------------
__device__ __forceinline__ float cubic_w(float q) {
    if (q <= 0.5f) return 2.0f / 3.0f + q * q * (4.0f * q - 4.0f);
    if (q <= 1.0f) return 4.0f / 3.0f + q * (-4.0f + q * (4.0f - (4.0f / 3.0f) * q));
    return 0.0f;
}

// ---------------------------------------------------------------------------
// Kernel 2 (fused): one block per query point b.
//  Phase 0: per-block redundant reduce of mind[] -> inv_dil, r^2 cutoff
//  Phase 1: SINGLE node sweep; per-4-node-group early-out on
//           min(d^2) > r2m (skipped groups contribute exactly 0 to M and
//           get w=0 cached). dx/dy/w cached in 48 VGPRs; in-support
//           group bitmask kept for the epilogue.
//  Phase 2: tid 0 analytic adjugate inverse (negated deriv rows)
//  Phase 3: pure-register epilogue; out-of-support groups store a zero
//           fx4 directly (no FMAs). Plain cached stores — output fits in
//           the 256 MiB L3, so do NOT bypass it (NT regressed in R2).
// ---------------------------------------------------------------------------
__global__ __launch_bounds__(256, 4) void rkpm_kernel(
        const float* __restrict__ x, const float* __restrict__ nodes,
        const float* __restrict__ mind, float* __restrict__ out) {
    __shared__ float sred[4][6];
    __shared__ float sbc[10];

    const int b = blockIdx.x;
    const int tid = threadIdx.x;
    const int wave = tid >> 6;
    const int lane = tid & 63;

    // ---- phase 0: dilation from mind[] ----
    const fx4* m4 = (const fx4*)mind;
    float s = 0.f;
    #pragma unroll
    for (int k = 0; k < 4; ++k) {
        fx4 v = m4[k * 256 + tid];
        s += (v.x + v.y) + (v.z + v.w);
    }
    #pragma unroll
    for (int off = 32; off > 0; off >>= 1)
        s += __shfl_down(s, off, 64);
    if (lane == 0) sred[wave][0] = s;
    __syncthreads();
    if (tid == 0) {
        float dil = (sred[0][0] + sred[1][0] + sred[2][0] + sred[3][0]) *
                    (SUPPORT_FACTOR / (float)N_NODES);
        sbc[0] = 1.0f / dil;
        // margin 2e-4 relative >> sqrt/div rounding: never skips a w!=0 node
        sbc[1] = dil * dil * 1.0002f + 1e-9f;
    }
    __syncthreads();
    const float inv_dil = sbc[0];
    const float r2m     = sbc[1];

    const float2 xq = ((const float2*)x)[b];
    const float xb = xq.x, yb = xq.y;

    // ---- phase 1: single sweep, cache w/dx/dy, group early-out ----
    const fx4* nodes4 = (const fx4*)nodes;   // 2 nodes per fx4
    float wr[16], dxr[16], dyr[16];
    int gmask = 0;                            // bit kk = group in support
    float m00 = 0.f, m01 = 0.f, m02 = 0.f, m11 = 0.f, m12 = 0.f, m22 = 0.f;
    #pragma unroll
    for (int kk = 0; kk < 4; ++kk) {
        fx4 va = nodes4[kk * 512 + 2 * tid];      // nodes j, j+1
        fx4 vb = nodes4[kk * 512 + 2 * tid + 1];  // nodes j+2, j+3
        const int r = kk * 4;
        float dx0 = xb - va.x, dy0 = yb - va.y;
        float dx1 = xb - va.z, dy1 = yb - va.w;
        float dx2 = xb - vb.x, dy2 = yb - vb.y;
        float dx3 = xb - vb.z, dy3 = yb - vb.w;
        dxr[r] = dx0; dyr[r] = dy0;
        dxr[r + 1] = dx1; dyr[r + 1] = dy1;
        dxr[r + 2] = dx2; dyr[r + 2] = dy2;
        dxr[r + 3] = dx3; dyr[r + 3] = dy3;
        float d0 = dx0 * dx0 + dy0 * dy0;
        float d1 = dx1 * dx1 + dy1 * dy1;
        float d2 = dx2 * dx2 + dy2 * dy2;
        float d3 = dx3 * dx3 + dy3 * dy3;
        float dmin = fminf(fminf(d0, d1), fminf(d2, d3));
        if (dmin <= r2m) {
            gmask |= (1 << kk);
            float w0 = cubic_w(sqrtf(d0 + 1e-10f) * inv_dil);
            float w1 = cubic_w(sqrtf(d1 + 1e-10f) * inv_dil);
            float w2 = cubic_w(sqrtf(d2 + 1e-10f) * inv_dil);
            float w3 = cubic_w(sqrtf(d3 + 1e-10f) * inv_dil);
            wr[r] = w0; wr[r + 1] = w1; wr[r + 2] = w2; wr[r + 3] = w3;
            m00 += (w0 + w1) + (w2 + w3);
            m01 += (w0 * dx0 + w1 * dx1) + (w2 * dx2 + w3 * dx3);
            m02 += (w0 * dy0 + w1 * dy1) + (w2 * dy2 + w3 * dy3);
            m11 += (w0 * dx0 * dx0 + w1 * dx1 * dx1) + (w2 * dx2 * dx2 + w3 * dx3 * dx3);
            m12 += (w0 * dx0 * dy0 + w1 * dx1 * dy1) + (w2 * dx2 * dy2 + w3 * dx3 * dy3);
            m22 += (w0 * dy0 * dy0 + w1 * dy1 * dy1) + (w2 * dy2 * dy2 + w3 * dy3 * dy3);
        } else {
            wr[r] = 0.f; wr[r + 1] = 0.f; wr[r + 2] = 0.f; wr[r + 3] = 0.f;
        }
    }
    #pragma unroll
    for (int off = 32; off > 0; off >>= 1) {
        m00 += __shfl_down(m00, off, 64);
        m01 += __shfl_down(m01, off, 64);
        m02 += __shfl_down(m02, off, 64);
        m11 += __shfl_down(m11, off, 64);
        m12 += __shfl_down(m12, off, 64);
        m22 += __shfl_down(m22, off, 64);
    }
    if (lane == 0) {
        sred[wave][0] = m00; sred[wave][1] = m01; sred[wave][2] = m02;
        sred[wave][3] = m11; sred[wave][4] = m12; sred[wave][5] = m22;
    }
    __syncthreads();

    // ---- phase 2: analytic symmetric 3x3 inverse ----
    if (tid == 0) {
        float a  = sred[0][0] + sred[1][0] + sred[2][0] + sred[3][0] + EPSILON;
        float bb = sred[0][1] + sred[1][1] + sred[2][1] + sred[3][1];
        float c  = sred[0][2] + sred[1][2] + sred[2][2] + sred[3][2];
        float d  = sred[0][3] + sred[1][3] + sred[2][3] + sred[3][3] + EPSILON;
        float e  = sred[0][4] + sred[1][4] + sred[2][4] + sred[3][4];
        float f  = sred[0][5] + sred[1][5] + sred[2][5] + sred[3][5] + EPSILON;
        float c00 = d * f - e * e;
        float c01 = c * e - bb * f;
        float c02 = bb * e - c * d;
        float det = a * c00 + bb * c01 + c * c02;
        float idet = 1.0f / det;
        float i00 = c00 * idet;
        float i01 = c01 * idet;
        float i02 = c02 * idet;
        float i11 = (a * f - c * c) * idet;
        float i12 = (bb * c - a * e) * idet;
        float i22 = (a * d - bb * bb) * idet;
        sbc[1] = i00;  sbc[2] = i01;  sbc[3] = i02;   // phi row
        sbc[4] = -i01; sbc[5] = -i11; sbc[6] = -i12;  // phi_x row (negated)
        sbc[7] = -i02; sbc[8] = -i12; sbc[9] = -i22;  // phi_y row (negated)
    }
    __syncthreads();

    const float i00 = sbc[1], i01 = sbc[2], i02  = sbc[3];
    const float n01 = sbc[4], n11 = sbc[5], n12  = sbc[6];
    const float n02 = sbc[7], n12b = sbc[8], n22 = sbc[9];

    const size_t BN = (size_t)B_PTS * N_NODES;
    fx4* __restrict__ out_phi = (fx4*)(out + (size_t)b * N_NODES);
    fx4* __restrict__ out_px  = (fx4*)(out + BN + (size_t)b * N_NODES);
    fx4* __restrict__ out_py  = (fx4*)(out + 2 * BN + (size_t)b * N_NODES);

    // ---- phase 3: pure-register epilogue, zero fast-path per group ----
    #pragma unroll
    for (int kk = 0; kk < 4; ++kk) {
        const int idx = kk * 256 + tid;
        fx4 ph = {0.f, 0.f, 0.f, 0.f};
        fx4 px = {0.f, 0.f, 0.f, 0.f};
        fx4 py = {0.f, 0.f, 0.f, 0.f};
        if (gmask & (1 << kk)) {
            #pragma unroll
            for (int c = 0; c < 4; ++c) {
                const int r = kk * 4 + c;
                float w = wr[r], dx = dxr[r], dy = dyr[r];
                float vph = w * (i00 + i01 * dx + i02 * dy);
                float vpx = w * (n01 + n11 * dx + n12 * dy);
                float vpy = w * (n02 + n12b * dx + n22 * dy);
                if (c == 0)      { ph.x = vph; px.x = vpx; py.x = vpy; }
                else if (c == 1) { ph.y = vph; px.y = vpx; py.y = vpy; }
                else if (c == 2) { ph.z = vph; px.z = vpx; py.z = vpy; }
                else             { ph.w = vph; px.w = vpx; py.w = vpy; }
            }
        }
        out_phi[idx] = ph;
        out_px[idx]  = px;
        out_py[idx]  = py;
    }
}

extern "C" void kernel_launch(void* const* d_in, const int* in_sizes, int n_in,
                              void* d_out, int out_size, void* d_ws, size_t ws_size,
                              hipStream_t stream) {
    const float* x     = (const float*)d_in[0];   // [4096, 2]
    const float* nodes = (const float*)d_in[1];   // [4096, 2]
    float* out  = (float*)d_out;                  // 3 * 4096 * 4096 floats
    float* mind = (float*)d_ws;                   // [4096] nearest distances

    nearest_kernel<<<N_NODES, 256, 0, stream>>>(nodes, mind);
    rkpm_kernel<<<B_PTS, 256, 0, stream>>>(x, nodes, mind, out);
}